// Round 1
// baseline (719.552 us; speedup 1.0000x reference)
//
#include <hip/hip_runtime.h>
#include <math.h>

typedef unsigned short u16;
typedef unsigned int   u32;
typedef __attribute__((ext_vector_type(8))) short bh8;   // 8 bf16 (4 VGPR)
typedef __attribute__((ext_vector_type(4))) float f4;    // 4 fp32 acc

#define TM 128
#define TN 128
#define TK 64   // K-step; LDS rows are 128 B, XOR-swizzled (see GEMM)

__device__ __forceinline__ u16 f2b(float f) {
  u32 u = __builtin_bit_cast(u32, f);
  u += 0x7fffu + ((u >> 16) & 1u);   // round-to-nearest-even
  return (u16)(u >> 16);
}
__device__ __forceinline__ float gelu_f(float x) {
  return 0.5f * x * (1.0f + erff(x * 0.70710678118654752f));
}

// async global -> LDS, 16 B per lane; lds base must be wave-uniform
__device__ __forceinline__ void gl2lds16(const u16* g, u16* l) {
  __builtin_amdgcn_global_load_lds(
      (const __attribute__((address_space(1))) u32*)g,
      (__attribute__((address_space(3))) u32*)l, 16, 0, 0);
}

// ---------------- routing ----------------
__global__ __launch_bounds__(128) void init_routing(int* __restrict__ R) {
  R[threadIdx.x] = 0;
}

__global__ __launch_bounds__(256) void hist_kernel(const int* __restrict__ eidx,
                                                   const int* __restrict__ hasp,
                                                   int* __restrict__ R,
                                                   int* __restrict__ grp) {
  int t = blockIdx.x * 256 + threadIdx.x;
  int g = eidx[t] * 2 + (hasp[t] != 0 ? 1 : 0);
  grp[t] = g;
  atomicAdd(&R[g], 1);
}

__global__ __launch_bounds__(64) void scan_kernel(int* __restrict__ R) {
  if (threadIdx.x == 0) {
    int* cnt = R; int* cur = R + 16; int* gs = R + 32; int* to = R + 64;
    gs[0] = 0; to[0] = 0;
    for (int g = 0; g < 16; g++) {
      gs[g + 1] = gs[g] + cnt[g];
      cur[g] = gs[g];
      to[g + 1] = to[g] + (cnt[g] + TM - 1) / TM;
    }
  }
}

__global__ __launch_bounds__(256) void scatter_kernel(const int* __restrict__ grp,
                                                      int* __restrict__ R,
                                                      int* __restrict__ perm) {
  int t = blockIdx.x * 256 + threadIdx.x;
  int g = grp[t];
  int pos = atomicAdd(&R[16 + g], 1);
  perm[pos] = t;
}

// gather raw_state (fp32) into grouped order, convert to bf16
__global__ __launch_bounds__(256) void gather_kernel(const float* __restrict__ raw,
                                                     const int* __restrict__ perm,
                                                     u16* __restrict__ Xg) {
  int t = blockIdx.x * 256 + threadIdx.x;
  int pos = t >> 6, ln = t & 63;
  int orig = perm[pos];
  Xg[(size_t)pos * 64 + ln] = f2b(raw[(size_t)orig * 64 + ln]);
}

// ------- weight transpose+convert: src fp32 [R][C] -> dst bf16 [C][R], 64x64 tiles -------
__global__ __launch_bounds__(256) void transpose_cvt(const float* __restrict__ srcP,
                                                     const float* __restrict__ srcQ,
                                                     int twoSrc, int Rr, int Cc,
                                                     u16* __restrict__ dst) {
  int m = blockIdx.z;
  const float* src = twoSrc ? (((m & 1) ? srcQ : srcP) + (size_t)(m >> 1) * Rr * Cc)
                            : (srcP + (size_t)m * Rr * Cc);
  u16* d = dst + (size_t)m * Rr * Cc;
  __shared__ u16 t[64][66];   // stride 66 u16 = 33 dword -> 2-way bank alias (free)
  int c0 = blockIdx.x * 64, r0 = blockIdx.y * 64;
  int tx = threadIdx.x, ty = threadIdx.y;   // 64 x 4
#pragma unroll
  for (int i = 0; i < 16; i++) {
    int r = ty + i * 4;
    t[tx][r] = f2b(src[(size_t)(r0 + r) * Cc + c0 + tx]);   // 256B coalesced read / wave
  }
  __syncthreads();
#pragma unroll
  for (int i = 0; i < 16; i++) {
    int c = ty + i * 4;
    d[(size_t)(c0 + c) * Rr + r0 + tx] = t[c][tx];          // 128B coalesced write / wave
  }
}

// ---------------- grouped GEMM: C[M,N] = A[M,K] * W^T (W stored [N][K] bf16) ----------------
// 2-phase pipelined (T3-min), double-buffered LDS, TK=64.
// LDS layout per buffer: [128 rows][64 k] bf16, rows 128 B.  XOR swizzle (T2, rule #21):
//   logical 16B-chunk ch of row r lives at physical chunk ch ^ (r & 7).
//   global_load_lds dest stays LINEAR; the *global source* chunk is pre-swizzled
//   ((lane&7) ^ (lane>>3)); ds_read applies the same involution -> conflict-free.
__global__ __launch_bounds__(256)
void gemm_grouped(const u16* __restrict__ A, int lda,
                  const u16* __restrict__ W, int wShift, int K, int N,
                  const float* __restrict__ biasP, const float* __restrict__ biasQ,
                  int branchBias, int doGelu,
                  u16* __restrict__ outB, float* __restrict__ outF,
                  int doScatter, int ldo,
                  const int* __restrict__ gstart, const int* __restrict__ tileOff,
                  const int* __restrict__ perm) {
  __shared__ __align__(16) u16 As[2][TM * TK];   // 2 x 16 KB
  __shared__ __align__(16) u16 Bs[2][TN * TK];   // 2 x 16 KB  (total 64 KB -> 2 blk/CU)

  int bidM = blockIdx.x;
  int tot = tileOff[16];
  if (bidM >= tot) return;
  int g = 0;
  while (g < 15 && bidM >= tileOff[g + 1]) g++;
  int rowStart = gstart[g] + (bidM - tileOff[g]) * TM;
  int rowEnd = gstart[g + 1];

  const u16* Wg = W + (size_t)(g >> wShift) * N * K;
  int e = g >> 1;
  const float* bias = ((branchBias && (g & 1)) ? biasQ : biasP) + (size_t)e * N;

  int tid = threadIdx.x;
  int lane = tid & 63;
  int wv = tid >> 6;
  int wm = (wv >> 1) * 64, wn = (wv & 1) * 64;
  int l15 = lane & 15, l4 = lane >> 4;
  int colBase = blockIdx.y * TN;

  // staging geometry: per K-step each matrix tile = 16 KB = 16 chunks of 1 KB
  // (64 lanes x 16 B).  Wave wv owns chunks wv*4 .. wv*4+3.  Chunk c covers tile
  // rows 8c..8c+7; lane covers row 8c + (lane>>3), 16B-unit (lane&7), with the
  // source column-chunk XOR-pre-swizzled.
  int rsub = lane >> 3;                 // 0..7: row within chunk
  int schunk = (lane & 7) ^ rsub;       // pre-swizzled source 16B-chunk (row&7 == rsub)
  int c0 = wv * 4;
  const u16* aSrc[4];
  const u16* bSrc[4];
#pragma unroll
  for (int q = 0; q < 4; q++) {
    int rt = (c0 + q) * 8 + rsub;
    int ga = rowStart + rt; ga = ga < rowEnd ? ga : (rowEnd - 1);
    aSrc[q] = A + (size_t)ga * lda + schunk * 8;
    bSrc[q] = Wg + (size_t)(colBase + rt) * K + schunk * 8;
  }

  f4 acc[4][4];
#pragma unroll
  for (int i = 0; i < 4; i++)
#pragma unroll
    for (int j = 0; j < 4; j++) acc[i][j] = (f4){0.f, 0.f, 0.f, 0.f};

  int rx = l15 & 7;                     // row&7 for all fragment rows (wm,16 are mult of 8)
  int aBase = (wm + l15) * TK;
  int bBase = (wn + l15) * TK;

#define STAGE(buf, k0)                                                        \
  do {                                                                        \
    _Pragma("unroll")                                                         \
    for (int q = 0; q < 4; q++) {                                             \
      gl2lds16(aSrc[q] + (k0), &As[(buf)][(c0 + q) * 512]);                   \
      gl2lds16(bSrc[q] + (k0), &Bs[(buf)][(c0 + q) * 512]);                   \
    }                                                                         \
  } while (0)

#define COMPUTE(buf)                                                          \
  do {                                                                        \
    _Pragma("unroll")                                                         \
    for (int ks = 0; ks < 2; ks++) {                                          \
      int ch = ((ks << 2) | l4) ^ rx;                                         \
      bh8 a[4], b[4];                                                         \
      _Pragma("unroll")                                                       \
      for (int i = 0; i < 4; i++)                                             \
        a[i] = *reinterpret_cast<const bh8*>(                                 \
            &As[(buf)][aBase + i * (16 * TK) + ch * 8]);                      \
      _Pragma("unroll")                                                       \
      for (int j = 0; j < 4; j++)                                             \
        b[j] = *reinterpret_cast<const bh8*>(                                 \
            &Bs[(buf)][bBase + j * (16 * TK) + ch * 8]);                      \
      _Pragma("unroll")                                                       \
      for (int i = 0; i < 4; i++)                                             \
        _Pragma("unroll")                                                     \
        for (int j = 0; j < 4; j++)                                           \
          acc[i][j] = __builtin_amdgcn_mfma_f32_16x16x32_bf16(                \
              a[i], b[j], acc[i][j], 0, 0, 0);                                \
    }                                                                         \
  } while (0)

  int nk = K / TK;
  // prologue: fill buffer 0 (syncthreads drains vmcnt(0) + lgkmcnt(0))
  STAGE(0, 0);
  __syncthreads();
  int cur = 0;
  for (int t = 1; t < nk; ++t) {
    STAGE(cur ^ 1, t * TK);   // issue next tile FIRST: latency hides under MFMA below
    COMPUTE(cur);             // ds_read (lgkm-waited by compiler) + 32 MFMA / wave
    __syncthreads();          // drains this wave's staging; all waves' reads of cur done
    cur ^= 1;
  }
  COMPUTE(cur);               // epilogue tile, no prefetch

  // epilogue: C row = rowStart + wm + i*16 + l4*4 + r ; col = colBase + wn + j*16 + l15
#pragma unroll
  for (int i = 0; i < 4; i++) {
#pragma unroll
    for (int r = 0; r < 4; r++) {
      int row = rowStart + wm + i * 16 + l4 * 4 + r;
      if (row < rowEnd) {
        int orow = doScatter ? perm[row] : row;
#pragma unroll
        for (int j = 0; j < 4; j++) {
          int col = colBase + wn + j * 16 + l15;
          float v = acc[i][j][r] + bias[col];
          if (doGelu) v = gelu_f(v);
          if (outF) outF[(size_t)orow * ldo + col] = v;
          else      outB[(size_t)orow * ldo + col] = f2b(v);
        }
      }
    }
  }
#undef STAGE
#undef COMPUTE
}

// ---------------- LayerNorm over D=1024, grouped rows (fp32 in, bf16 out) ----------------
__global__ __launch_bounds__(256) void ln_kernel(const float* __restrict__ MIX,
                                                 u16* __restrict__ NRM,
                                                 const float* __restrict__ lng,
                                                 const float* __restrict__ lnb,
                                                 const int* __restrict__ gstart) {
  const int D = 1024;
  int pos = blockIdx.x;
  int g = 0;
  while (g < 15 && pos >= gstart[g + 1]) g++;
  int e = g >> 1;
  int tid = threadIdx.x;
  float x[4];
  float s = 0.f, s2 = 0.f;
#pragma unroll
  for (int i = 0; i < 4; i++) {
    float v = MIX[(size_t)pos * D + tid + i * 256];
    x[i] = v; s += v; s2 += v * v;
  }
#pragma unroll
  for (int off = 32; off >= 1; off >>= 1) {
    s += __shfl_down(s, off);
    s2 += __shfl_down(s2, off);
  }
  __shared__ float red[8];
  int wv = tid >> 6;
  if ((tid & 63) == 0) { red[wv] = s; red[4 + wv] = s2; }
  __syncthreads();
  if (tid == 0) {
    red[0] = red[0] + red[1] + red[2] + red[3];
    red[4] = red[4] + red[5] + red[6] + red[7];
  }
  __syncthreads();
  float mean = red[0] / D;
  float var = red[4] / D - mean * mean;
  float rstd = rsqrtf(var + 1e-5f);
#pragma unroll
  for (int i = 0; i < 4; i++) {
    int c = tid + i * 256;
    float v = (x[i] - mean) * rstd * lng[(size_t)e * D + c] + lnb[(size_t)e * D + c];
    NRM[(size_t)pos * D + c] = f2b(v);
  }
}

extern "C" void kernel_launch(void* const* d_in, const int* in_sizes, int n_in,
                              void* d_out, int out_size, void* d_ws, size_t ws_size,
                              hipStream_t stream) {
  const float* raw = (const float*)d_in[0];
  const int* hasp = (const int*)d_in[1];
  const int* eidx = (const int*)d_in[2];
  const float* pw1 = (const float*)d_in[3];  const float* pb1 = (const float*)d_in[4];
  const float* pw2 = (const float*)d_in[5];  const float* pb2 = (const float*)d_in[6];
  const float* qw1 = (const float*)d_in[7];  const float* qb1 = (const float*)d_in[8];
  const float* qw2 = (const float*)d_in[9];  const float* qb2 = (const float*)d_in[10];
  const float* lng = (const float*)d_in[11]; const float* lnb = (const float*)d_in[12];
  const float* tw1 = (const float*)d_in[13]; const float* tb1 = (const float*)d_in[14];
  const float* tw2 = (const float*)d_in[15]; const float* tb2 = (const float*)d_in[16];
  float* out = (float*)d_out;

  const int B = in_sizes[0] / 64;   // 8192
  const int S = 64, H = 2048, D = 1024, E = 8;

  char* ws = (char*)d_ws;
  size_t o = 0;
  int* R    = (int*)(ws + o); o += 1024;
  int* grp  = (int*)(ws + o); o += (size_t)B * 4;
  int* perm = (int*)(ws + o); o += (size_t)B * 4;
  u16* Xg   = (u16*)(ws + o); o += (size_t)B * S * 2;
  u16* Hbuf = (u16*)(ws + o); o += (size_t)B * H * 2;
  float* MIX = (float*)(ws + o); o += (size_t)B * D * 4;
  u16* NRM  = (u16*)(ws + o); o += (size_t)B * D * 2;
  u16* W1T  = (u16*)(ws + o); o += (size_t)2 * E * S * H * 2;
  u16* WB   = (u16*)(ws + o);                      // 64MB region, reused
  u16* T1T  = WB;
  u16* T2T  = WB + (size_t)E * D * H;

  int* gstart = R + 32;
  int* toff = R + 64;

  // routing
  init_routing<<<1, 128, 0, stream>>>(R);
  hist_kernel<<<B / 256, 256, 0, stream>>>(eidx, hasp, R, grp);
  scan_kernel<<<1, 64, 0, stream>>>(R);
  scatter_kernel<<<B / 256, 256, 0, stream>>>(grp, R, perm);
  gather_kernel<<<B / 4, 256, 0, stream>>>(raw, perm, Xg);

  dim3 tb(64, 4);
  // W1: [S=64][H=2048] x16 -> [H][S] bf16
  transpose_cvt<<<dim3(H / 64, S / 64, 16), tb, 0, stream>>>(pw1, qw1, 1, S, H, W1T);
  // W2: [H][D] x16 -> [D][H] bf16
  transpose_cvt<<<dim3(D / 64, H / 64, 16), tb, 0, stream>>>(pw2, qw2, 1, H, D, WB);

  const int maxT = B / TM + 16;
  // stage1: [B,64] x [64,2048] -> gelu -> Hbuf (bf16)
  gemm_grouped<<<dim3(maxT, H / TN), 256, 0, stream>>>(
      Xg, S, W1T, 0, S, H, pb1, qb1, 1, 1, Hbuf, nullptr, 0, H, gstart, toff, perm);
  // stage2: [B,2048] x [2048,1024] -> MIX (fp32)
  gemm_grouped<<<dim3(maxT, D / TN), 256, 0, stream>>>(
      Hbuf, H, WB, 0, H, D, pb2, qb2, 1, 0, nullptr, MIX, 0, D, gstart, toff, perm);
  // LayerNorm
  ln_kernel<<<B, 256, 0, stream>>>(MIX, NRM, lng, lnb, gstart);
  // T1: [D][H] x8 -> [H][D] ; T2: [H][D] x8 -> [D][H]  (overwrites WB, stage2 done)
  transpose_cvt<<<dim3(H / 64, D / 64, 8), tb, 0, stream>>>(tw1, nullptr, 0, D, H, T1T);
  transpose_cvt<<<dim3(D / 64, H / 64, 8), tb, 0, stream>>>(tw2, nullptr, 0, H, D, T2T);
  // stage3: [B,1024] x [1024,2048] -> gelu -> Hbuf (bf16)
  gemm_grouped<<<dim3(maxT, H / TN), 256, 0, stream>>>(
      NRM, D, T1T, 1, D, H, tb1, nullptr, 0, 1, Hbuf, nullptr, 0, H, gstart, toff, perm);
  // stage4: [B,2048] x [2048,1024] -> scatter fp32 to out
  gemm_grouped<<<dim3(maxT, D / TN), 256, 0, stream>>>(
      Hbuf, H, T2T, 1, H, D, tb2, nullptr, 0, 0, nullptr, out, 1, D, gstart, toff, perm);
}

// Round 2
// 631.255 us; speedup vs baseline: 1.1399x; 1.1399x over previous
//
#include <hip/hip_runtime.h>
#include <math.h>

typedef unsigned short u16;
typedef unsigned int   u32;
typedef __attribute__((ext_vector_type(8))) short bh8;   // 8 bf16 (4 VGPR)
typedef __attribute__((ext_vector_type(4))) float f4;    // 4 fp32 acc

#define TM 128
#define TN 64
#define TK 32   // K-step; LDS rows 64 B; unit-XOR swizzle (see GEMM)

__device__ __forceinline__ u16 f2b(float f) {
  u32 u = __builtin_bit_cast(u32, f);
  u += 0x7fffu + ((u >> 16) & 1u);   // round-to-nearest-even
  return (u16)(u >> 16);
}
__device__ __forceinline__ float gelu_f(float x) {
  return 0.5f * x * (1.0f + erff(x * 0.70710678118654752f));
}

// async global -> LDS, 16 B per lane; lds base must be wave-uniform
__device__ __forceinline__ void gl2lds16(const u16* g, u16* l) {
  __builtin_amdgcn_global_load_lds(
      (const __attribute__((address_space(1))) u32*)g,
      (__attribute__((address_space(3))) u32*)l, 16, 0, 0);
}

// ---------------- routing ----------------
__global__ __launch_bounds__(128) void init_routing(int* __restrict__ R) {
  R[threadIdx.x] = 0;
}

__global__ __launch_bounds__(256) void hist_kernel(const int* __restrict__ eidx,
                                                   const int* __restrict__ hasp,
                                                   int* __restrict__ R,
                                                   int* __restrict__ grp) {
  int t = blockIdx.x * 256 + threadIdx.x;
  int g = eidx[t] * 2 + (hasp[t] != 0 ? 1 : 0);
  grp[t] = g;
  atomicAdd(&R[g], 1);
}

__global__ __launch_bounds__(64) void scan_kernel(int* __restrict__ R) {
  if (threadIdx.x == 0) {
    int* cnt = R; int* cur = R + 16; int* gs = R + 32; int* to = R + 64;
    gs[0] = 0; to[0] = 0;
    for (int g = 0; g < 16; g++) {
      gs[g + 1] = gs[g] + cnt[g];
      cur[g] = gs[g];
      to[g + 1] = to[g] + (cnt[g] + TM - 1) / TM;
    }
  }
}

__global__ __launch_bounds__(256) void scatter_kernel(const int* __restrict__ grp,
                                                      int* __restrict__ R,
                                                      int* __restrict__ perm) {
  int t = blockIdx.x * 256 + threadIdx.x;
  int g = grp[t];
  int pos = atomicAdd(&R[16 + g], 1);
  perm[pos] = t;
}

// gather raw_state (fp32) into grouped order, convert to bf16
__global__ __launch_bounds__(256) void gather_kernel(const float* __restrict__ raw,
                                                     const int* __restrict__ perm,
                                                     u16* __restrict__ Xg) {
  int t = blockIdx.x * 256 + threadIdx.x;
  int pos = t >> 6, ln = t & 63;
  int orig = perm[pos];
  Xg[(size_t)pos * 64 + ln] = f2b(raw[(size_t)orig * 64 + ln]);
}

// ------- weight transpose+convert: src fp32 [R][C] -> dst bf16 [C][R], 64x64 tiles -------
__global__ __launch_bounds__(256) void transpose_cvt(const float* __restrict__ srcP,
                                                     const float* __restrict__ srcQ,
                                                     int twoSrc, int Rr, int Cc,
                                                     u16* __restrict__ dst) {
  int m = blockIdx.z;
  const float* src = twoSrc ? (((m & 1) ? srcQ : srcP) + (size_t)(m >> 1) * Rr * Cc)
                            : (srcP + (size_t)m * Rr * Cc);
  u16* d = dst + (size_t)m * Rr * Cc;
  __shared__ u16 t[64][66];   // stride 66 u16 = 33 dword -> 2-way bank alias (free)
  int c0 = blockIdx.x * 64, r0 = blockIdx.y * 64;
  int tx = threadIdx.x, ty = threadIdx.y;   // 64 x 4
#pragma unroll
  for (int i = 0; i < 16; i++) {
    int r = ty + i * 4;
    t[tx][r] = f2b(src[(size_t)(r0 + r) * Cc + c0 + tx]);   // 256B coalesced read / wave
  }
  __syncthreads();
#pragma unroll
  for (int i = 0; i < 16; i++) {
    int c = ty + i * 4;
    d[(size_t)(c0 + c) * Rr + r0 + tx] = t[c][tx];          // 128B coalesced write / wave
  }
}

// ---------------- grouped GEMM: C[M,N] = A[M,K] * W^T (W stored [N][K] bf16) ----------------
// 2-phase pipelined, double-buffered LDS, TM=128 TN=64 TK=32 (24 KB LDS -> ~5 blk/CU).
// LDS layout per buffer: [rows][32 k] bf16, rows 64 B = 4 16B-units.  Swizzle (rule #21,
// both-sides): logical unit u of row r lives at physical u ^ ((r>>1)&3).
//   - global_load_lds dest stays LINEAR; the *global source* unit is pre-swizzled.
//   - ds_read applies the same involution -> 2-way residual alias (free).
__global__ __launch_bounds__(256)
void gemm_grouped(const u16* __restrict__ A, int lda,
                  const u16* __restrict__ W, int wShift, int K, int N,
                  const float* __restrict__ biasP, const float* __restrict__ biasQ,
                  int branchBias, int doGelu,
                  u16* __restrict__ outB, float* __restrict__ outF,
                  int doScatter, int ldo,
                  const int* __restrict__ gstart, const int* __restrict__ tileOff,
                  const int* __restrict__ perm) {
  __shared__ __align__(16) u16 As[2][TM * TK];   // 2 x 8 KB
  __shared__ __align__(16) u16 Bs[2][TN * TK];   // 2 x 4 KB  (24 KB total)

  int bidM = blockIdx.x;
  int tot = tileOff[16];
  if (bidM >= tot) return;
  int g = 0;
  while (g < 15 && bidM >= tileOff[g + 1]) g++;
  int rowStart = gstart[g] + (bidM - tileOff[g]) * TM;
  int rowEnd = gstart[g + 1];

  const u16* Wg = W + (size_t)(g >> wShift) * N * K;
  int e = g >> 1;
  const float* bias = ((branchBias && (g & 1)) ? biasQ : biasP) + (size_t)e * N;

  int tid = threadIdx.x;
  int lane = tid & 63;
  int wv = tid >> 6;
  int wm = (wv >> 1) * 64, wn = (wv & 1) * 32;   // wave sub-tile 64x32
  int l15 = lane & 15, l4 = lane >> 4;
  int colBase = blockIdx.y * TN;

  // staging geometry: 1 KB chunk = 64 lanes x 16 B = 16 rows of 64 B.
  // A-tile (128x32) = 8 chunks, B-tile (64x32) = 4 chunks.  Wave wv owns
  // A chunks {2wv, 2wv+1} and B chunk {wv}.  Lane covers row 16c + (lane>>2),
  // 16B-unit lane&3, with the source unit XOR-pre-swizzled.
  int rsub = lane >> 2;                       // 0..15: row within chunk
  int su = (lane & 3) ^ ((rsub >> 1) & 3);    // pre-swizzled source 16B unit
  int cA = wv * 2;
  int rtA0 = cA * 16 + rsub;
  int rtA1 = rtA0 + 16;
  int rtB = wv * 16 + rsub;
  int ga0 = rowStart + rtA0; ga0 = ga0 < rowEnd ? ga0 : (rowEnd - 1);
  int ga1 = rowStart + rtA1; ga1 = ga1 < rowEnd ? ga1 : (rowEnd - 1);
  const u16* aSrc0 = A + (size_t)ga0 * lda + su * 8;
  const u16* aSrc1 = A + (size_t)ga1 * lda + su * 8;
  const u16* bSrc  = Wg + (size_t)(colBase + rtB) * K + su * 8;

  f4 acc[4][2];
#pragma unroll
  for (int i = 0; i < 4; i++)
#pragma unroll
    for (int j = 0; j < 2; j++) acc[i][j] = (f4){0.f, 0.f, 0.f, 0.f};

  int rx = (l15 >> 1) & 3;                    // (row>>1)&3 for all fragment rows
  int ch = l4 ^ rx;                           // physical 16B unit to read
  int aBase = (wm + l15) * TK + ch * 8;
  int bBase = (wn + l15) * TK + ch * 8;

#define STAGE(buf, k0)                                                        \
  do {                                                                        \
    gl2lds16(aSrc0 + (k0), &As[(buf)][cA * 512]);                             \
    gl2lds16(aSrc1 + (k0), &As[(buf)][cA * 512 + 512]);                       \
    gl2lds16(bSrc + (k0), &Bs[(buf)][wv * 512]);                              \
  } while (0)

#define COMPUTE(buf)                                                          \
  do {                                                                        \
    bh8 a[4], b[2];                                                           \
    _Pragma("unroll")                                                         \
    for (int i = 0; i < 4; i++)                                               \
      a[i] = *reinterpret_cast<const bh8*>(&As[(buf)][aBase + i * (16 * TK)]);\
    _Pragma("unroll")                                                         \
    for (int j = 0; j < 2; j++)                                               \
      b[j] = *reinterpret_cast<const bh8*>(&Bs[(buf)][bBase + j * (16 * TK)]);\
    _Pragma("unroll")                                                         \
    for (int i = 0; i < 4; i++)                                               \
      _Pragma("unroll")                                                       \
      for (int j = 0; j < 2; j++)                                             \
        acc[i][j] = __builtin_amdgcn_mfma_f32_16x16x32_bf16(                  \
            a[i], b[j], acc[i][j], 0, 0, 0);                                  \
  } while (0)

  int nk = K / TK;
  // prologue: fill buffer 0 (syncthreads drains vmcnt(0) + lgkmcnt(0))
  STAGE(0, 0);
  __syncthreads();
  int cur = 0;
  for (int t = 1; t < nk; ++t) {
    STAGE(cur ^ 1, t * TK);   // issue next tile FIRST: latency hides under MFMA below
    COMPUTE(cur);             // ds_read + 8 MFMA / wave
    __syncthreads();          // drains this wave's staging; all waves' reads of cur done
    cur ^= 1;
  }
  COMPUTE(cur);               // epilogue tile, no prefetch

  // epilogue: C row = rowStart + wm + i*16 + l4*4 + r ; col = colBase + wn + j*16 + l15
#pragma unroll
  for (int i = 0; i < 4; i++) {
#pragma unroll
    for (int r = 0; r < 4; r++) {
      int row = rowStart + wm + i * 16 + l4 * 4 + r;
      if (row < rowEnd) {
        int orow = doScatter ? perm[row] : row;
#pragma unroll
        for (int j = 0; j < 2; j++) {
          int col = colBase + wn + j * 16 + l15;
          float v = acc[i][j][r] + bias[col];
          if (doGelu) v = gelu_f(v);
          if (outF) outF[(size_t)orow * ldo + col] = v;
          else      outB[(size_t)orow * ldo + col] = f2b(v);
        }
      }
    }
  }
#undef STAGE
#undef COMPUTE
}

// ---------------- LayerNorm over D=1024, grouped rows (fp32 in, bf16 out) ----------------
__global__ __launch_bounds__(256) void ln_kernel(const float* __restrict__ MIX,
                                                 u16* __restrict__ NRM,
                                                 const float* __restrict__ lng,
                                                 const float* __restrict__ lnb,
                                                 const int* __restrict__ gstart) {
  const int D = 1024;
  int pos = blockIdx.x;
  int g = 0;
  while (g < 15 && pos >= gstart[g + 1]) g++;
  int e = g >> 1;
  int tid = threadIdx.x;
  float x[4];
  float s = 0.f, s2 = 0.f;
#pragma unroll
  for (int i = 0; i < 4; i++) {
    float v = MIX[(size_t)pos * D + tid + i * 256];
    x[i] = v; s += v; s2 += v * v;
  }
#pragma unroll
  for (int off = 32; off >= 1; off >>= 1) {
    s += __shfl_down(s, off);
    s2 += __shfl_down(s2, off);
  }
  __shared__ float red[8];
  int wv = tid >> 6;
  if ((tid & 63) == 0) { red[wv] = s; red[4 + wv] = s2; }
  __syncthreads();
  if (tid == 0) {
    red[0] = red[0] + red[1] + red[2] + red[3];
    red[4] = red[4] + red[5] + red[6] + red[7];
  }
  __syncthreads();
  float mean = red[0] / D;
  float var = red[4] / D - mean * mean;
  float rstd = rsqrtf(var + 1e-5f);
#pragma unroll
  for (int i = 0; i < 4; i++) {
    int c = tid + i * 256;
    float v = (x[i] - mean) * rstd * lng[(size_t)e * D + c] + lnb[(size_t)e * D + c];
    NRM[(size_t)pos * D + c] = f2b(v);
  }
}

extern "C" void kernel_launch(void* const* d_in, const int* in_sizes, int n_in,
                              void* d_out, int out_size, void* d_ws, size_t ws_size,
                              hipStream_t stream) {
  const float* raw = (const float*)d_in[0];
  const int* hasp = (const int*)d_in[1];
  const int* eidx = (const int*)d_in[2];
  const float* pw1 = (const float*)d_in[3];  const float* pb1 = (const float*)d_in[4];
  const float* pw2 = (const float*)d_in[5];  const float* pb2 = (const float*)d_in[6];
  const float* qw1 = (const float*)d_in[7];  const float* qb1 = (const float*)d_in[8];
  const float* qw2 = (const float*)d_in[9];  const float* qb2 = (const float*)d_in[10];
  const float* lng = (const float*)d_in[11]; const float* lnb = (const float*)d_in[12];
  const float* tw1 = (const float*)d_in[13]; const float* tb1 = (const float*)d_in[14];
  const float* tw2 = (const float*)d_in[15]; const float* tb2 = (const float*)d_in[16];
  float* out = (float*)d_out;

  const int B = in_sizes[0] / 64;   // 8192
  const int S = 64, H = 2048, D = 1024, E = 8;

  char* ws = (char*)d_ws;
  size_t o = 0;
  int* R    = (int*)(ws + o); o += 1024;
  int* grp  = (int*)(ws + o); o += (size_t)B * 4;
  int* perm = (int*)(ws + o); o += (size_t)B * 4;
  u16* Xg   = (u16*)(ws + o); o += (size_t)B * S * 2;
  u16* Hbuf = (u16*)(ws + o); o += (size_t)B * H * 2;
  float* MIX = (float*)(ws + o); o += (size_t)B * D * 4;
  u16* NRM  = (u16*)(ws + o); o += (size_t)B * D * 2;
  u16* W1T  = (u16*)(ws + o); o += (size_t)2 * E * S * H * 2;
  u16* WB   = (u16*)(ws + o);                      // 64MB region, reused
  u16* T1T  = WB;
  u16* T2T  = WB + (size_t)E * D * H;

  int* gstart = R + 32;
  int* toff = R + 64;

  // routing
  init_routing<<<1, 128, 0, stream>>>(R);
  hist_kernel<<<B / 256, 256, 0, stream>>>(eidx, hasp, R, grp);
  scan_kernel<<<1, 64, 0, stream>>>(R);
  scatter_kernel<<<B / 256, 256, 0, stream>>>(grp, R, perm);
  gather_kernel<<<B / 4, 256, 0, stream>>>(raw, perm, Xg);

  dim3 tb(64, 4);
  // W1: [S=64][H=2048] x16 -> [H][S] bf16
  transpose_cvt<<<dim3(H / 64, S / 64, 16), tb, 0, stream>>>(pw1, qw1, 1, S, H, W1T);
  // W2: [H][D] x16 -> [D][H] bf16
  transpose_cvt<<<dim3(D / 64, H / 64, 16), tb, 0, stream>>>(pw2, qw2, 1, H, D, WB);

  const int maxT = B / TM + 16;
  // stage1: [B,64] x [64,2048] -> gelu -> Hbuf (bf16)
  gemm_grouped<<<dim3(maxT, H / TN), 256, 0, stream>>>(
      Xg, S, W1T, 0, S, H, pb1, qb1, 1, 1, Hbuf, nullptr, 0, H, gstart, toff, perm);
  // stage2: [B,2048] x [2048,1024] -> MIX (fp32)
  gemm_grouped<<<dim3(maxT, D / TN), 256, 0, stream>>>(
      Hbuf, H, WB, 0, H, D, pb2, qb2, 1, 0, nullptr, MIX, 0, D, gstart, toff, perm);
  // LayerNorm
  ln_kernel<<<B, 256, 0, stream>>>(MIX, NRM, lng, lnb, gstart);
  // T1: [D][H] x8 -> [H][D] ; T2: [H][D] x8 -> [D][H]  (overwrites WB, stage2 done)
  transpose_cvt<<<dim3(H / 64, D / 64, 8), tb, 0, stream>>>(tw1, nullptr, 0, D, H, T1T);
  transpose_cvt<<<dim3(D / 64, H / 64, 8), tb, 0, stream>>>(tw2, nullptr, 0, H, D, T2T);
  // stage3: [B,1024] x [1024,2048] -> gelu -> Hbuf (bf16)
  gemm_grouped<<<dim3(maxT, H / TN), 256, 0, stream>>>(
      NRM, D, T1T, 1, D, H, tb1, nullptr, 0, 1, Hbuf, nullptr, 0, H, gstart, toff, perm);
  // stage4: [B,2048] x [2048,1024] -> scatter fp32 to out
  gemm_grouped<<<dim3(maxT, D / TN), 256, 0, stream>>>(
      Hbuf, H, T2T, 1, H, D, tb2, nullptr, 0, 0, nullptr, out, 1, D, gstart, toff, perm);
}